// Round 5
// baseline (174.977 us; speedup 1.0000x reference)
//
#include <hip/hip_runtime.h>

#define NH  16
#define SQL 1024
#define SKV 4096
#define HD  128
#define TK  64

__device__ __forceinline__ float blo(unsigned u) { return __uint_as_float(u << 16); }
__device__ __forceinline__ float bhi(unsigned u) { return __uint_as_float(u & 0xFFFF0000u); }

__device__ __forceinline__ unsigned bfpack2(float x, float y) {
    unsigned ux = __float_as_uint(x), uy = __float_as_uint(y);
    ux = (ux + 0x7FFFu + ((ux >> 16) & 1u)) >> 16;           // RNE
    uy = (uy + 0x7FFFu + ((uy >> 16) & 1u)) & 0xFFFF0000u;   // RNE
    return ux | uy;
}

// ---- convert fp32 [H][SKV][HD] -> bf16 head-interleaved [SKV][H][HD] ----
// blocks 0..4095: K, 4096..8191: V. Block: fixed h, 16 skv rows.
__global__ __launch_bounds__(256) void cvt_hsi(
    const float* __restrict__ k, const float* __restrict__ v,
    unsigned short* __restrict__ kt, unsigned short* __restrict__ vt)
{
    int b = blockIdx.x;
    const float* src;
    unsigned short* dst;
    if (b < 4096) { src = k; dst = kt; }
    else          { src = v; dst = vt; b -= 4096; }
    const int h  = b & 15;
    const int i  = ((b >> 4) << 4) + (threadIdx.x >> 4);  // skv row
    const int c  = threadIdx.x & 15;                      // 8-elem dim chunk

    const float* sp = src + ((size_t)h * SKV + i) * HD + c * 8;
    float4 a = *(const float4*)sp;
    float4 d = *(const float4*)(sp + 4);
    uint4 o;
    o.x = bfpack2(a.x, a.y);
    o.y = bfpack2(a.z, a.w);
    o.z = bfpack2(d.x, d.y);
    o.w = bfpack2(d.z, d.w);
    *(uint4*)(dst + ((size_t)i * NH + h) * HD + c * 8) = o;
}

// ---- main: one block per s; all 16 heads; 4-KB contiguous gathers ----
__global__ __launch_bounds__(256) void dsa_hsi(
    const float* __restrict__ q, const unsigned short* __restrict__ kt,
    const unsigned short* __restrict__ vt, const int* __restrict__ tidx,
    const float* __restrict__ tsc, float* __restrict__ out)
{
    __shared__ int   idxs[TK];
    __shared__ float tscs[TK];
    __shared__ float wsc[NH][TK + 1];   // +1: break 4-way bank conflict on wsc[h][t]

    const int tid  = threadIdx.x;
    const int lane = tid & 63;
    const int wv   = tid >> 6;
    const int c    = lane & 15;             // dim chunk: dims 8c..8c+7
    const int h    = (wv << 2) | (lane >> 4);
    const int s    = blockIdx.x;

    if (tid < TK) {
        idxs[tid] = tidx[s * TK + tid];
        tscs[tid] = tsc[s * TK + tid];
    }

    // q fragment: 8 fp32 dims of head h
    const float* qp = q + ((size_t)h * SQL + s) * HD + c * 8;
    const float4 qa = *(const float4*)qp;
    const float4 qb = *(const float4*)(qp + 4);

    __syncthreads();
    const float myts = tscs[lane];

    // ---- QK^T: per t, block reads K'[idx_t] = 4 KB contiguous (1 KB/wave)
    const unsigned short* kbase = kt + h * HD + c * 8;
#pragma unroll 8
    for (int t = 0; t < TK; ++t) {
        const size_t row = (size_t)idxs[t];
        uint4 kw = *(const uint4*)(kbase + (row << 11));   // row*NH*HD
        float d;
        d  = qa.x * blo(kw.x) + qa.y * bhi(kw.x);
        d += qa.z * blo(kw.y) + qa.w * bhi(kw.y);
        d += qb.x * blo(kw.z) + qb.y * bhi(kw.z);
        d += qb.z * blo(kw.w) + qb.w * bhi(kw.w);
        d += __shfl_xor(d, 8);
        d += __shfl_xor(d, 4);
        d += __shfl_xor(d, 2);
        d += __shfl_xor(d, 1);
        if (c == 0) wsc[h][t] = d;          // wave-private rows of wsc
    }

    // ---- softmax * topk_scores, renormalized; wave handles its 4 heads
#pragma unroll
    for (int hh = 0; hh < 4; ++hh) {
        const int hx = (wv << 2) | hh;
        float a = wsc[hx][lane] * 0.08838834764831845f;    // 1/sqrt(128)
        float m = a;
#pragma unroll
        for (int off = 32; off; off >>= 1) m = fmaxf(m, __shfl_xor(m, off));
        const float e   = __expf(a - m);
        const float ets = e * myts;
        float se = e, sets = ets;
#pragma unroll
        for (int off = 32; off; off >>= 1) {
            se   += __shfl_xor(se, off);
            sets += __shfl_xor(sets, off);
        }
        wsc[hx][lane] = ets / (sets + 1e-12f * se);
    }

    // ---- PV: per t, block reads V'[idx_t] = 4 KB contiguous; thread owns
    // 8 output dims of head h -> no cross-lane combine.
    const unsigned short* vbase = vt + h * HD + c * 8;
    float o0=0.f,o1=0.f,o2=0.f,o3=0.f,o4=0.f,o5=0.f,o6=0.f,o7=0.f;
#pragma unroll 8
    for (int t = 0; t < TK; ++t) {
        const size_t row = (size_t)idxs[t];
        const float  wt  = wsc[h][t];       // 16-lane broadcast, padded stride
        uint4 vw = *(const uint4*)(vbase + (row << 11));
        o0 += wt * blo(vw.x);  o1 += wt * bhi(vw.x);
        o2 += wt * blo(vw.y);  o3 += wt * bhi(vw.y);
        o4 += wt * blo(vw.z);  o5 += wt * bhi(vw.z);
        o6 += wt * blo(vw.w);  o7 += wt * bhi(vw.w);
    }

    float* op = out + ((size_t)h * SQL + s) * HD + c * 8;
    *(float4*)op       = make_float4(o0, o1, o2, o3);
    *(float4*)(op + 4) = make_float4(o4, o5, o6, o7);
}

// ---- fp32 fallback (round-1 kernel) if workspace too small ----
__global__ __launch_bounds__(256) void dsa_fp32(
    const float* __restrict__ q, const float* __restrict__ k,
    const float* __restrict__ v, const int* __restrict__ tidx,
    const float* __restrict__ tsc, float* __restrict__ out)
{
    __shared__ int   idxs[4][TK];
    __shared__ float wsc[4][TK];
    const int tid = threadIdx.x, wv = tid >> 6, lane = tid & 63;
    const int half = lane >> 5, l32 = lane & 31, bi = blockIdx.x;
    const int h = ((bi & 7) << 1) | ((bi >> 3) & 1);
    const int s = ((bi >> 4) << 2) + wv;
    const float* qp = q + (size_t)(h * SQL + s) * HD;
    const float4 qf = *(const float4*)(qp + 4 * l32);
    const float t_sc = tsc[s * TK + lane];
    idxs[wv][lane] = tidx[s * TK + lane];
    const float* kb = k + (size_t)h * SKV * HD;
#pragma unroll 4
    for (int i = 0; i < TK / 2; ++i) {
        const int t = 2 * i + half, row = idxs[wv][t];
        float4 k4 = *(const float4*)(kb + (size_t)row * HD + 4 * l32);
        float d = k4.x * qf.x + k4.y * qf.y + k4.z * qf.z + k4.w * qf.w;
        d += __shfl_xor(d, 16); d += __shfl_xor(d, 8); d += __shfl_xor(d, 4);
        d += __shfl_xor(d, 2);  d += __shfl_xor(d, 1);
        if (l32 == 0) wsc[wv][t] = d;
    }
    float acc = wsc[wv][lane] * 0.08838834764831845f;
    float m = acc;
#pragma unroll
    for (int off = 32; off; off >>= 1) m = fmaxf(m, __shfl_xor(m, off));
    const float e = __expf(acc - m), ets = e * t_sc;
    float se = e, sets = ets;
#pragma unroll
    for (int off = 32; off; off >>= 1) { se += __shfl_xor(se, off); sets += __shfl_xor(sets, off); }
    wsc[wv][lane] = ets / (sets + 1e-12f * se);
    const float* vbp = v + (size_t)h * SKV * HD;
    float4 o = make_float4(0.f, 0.f, 0.f, 0.f);
#pragma unroll 4
    for (int i = 0; i < TK / 2; ++i) {
        const int t = 2 * i + half, row = idxs[wv][t];
        const float wt = wsc[wv][t];
        float4 v4 = *(const float4*)(vbp + (size_t)row * HD + 4 * l32);
        o.x += wt * v4.x; o.y += wt * v4.y; o.z += wt * v4.z; o.w += wt * v4.w;
    }
    o.x += __shfl_xor(o.x, 32); o.y += __shfl_xor(o.y, 32);
    o.z += __shfl_xor(o.z, 32); o.w += __shfl_xor(o.w, 32);
    if (half == 0) *(float4*)(out + (size_t)(h * SQL + s) * HD + 4 * l32) = o;
}

extern "C" void kernel_launch(void* const* d_in, const int* in_sizes, int n_in,
                              void* d_out, int out_size, void* d_ws, size_t ws_size,
                              hipStream_t stream) {
    const float* q  = (const float*)d_in[0];
    const float* k  = (const float*)d_in[1];
    const float* v  = (const float*)d_in[2];
    const int*   ti = (const int*)d_in[3];
    const float* ts = (const float*)d_in[4];
    float* out = (float*)d_out;

    const size_t nkv  = (size_t)NH * SKV * HD;            // 8.4M elems each
    const size_t need = 2 * nkv * sizeof(unsigned short); // 33.6 MB
    if (ws_size >= need) {
        unsigned short* kt = (unsigned short*)d_ws;
        unsigned short* vt = kt + nkv;
        cvt_hsi<<<dim3(8192), dim3(256), 0, stream>>>(k, v, kt, vt);
        dsa_hsi<<<dim3(SQL), dim3(256), 0, stream>>>(q, kt, vt, ti, ts, out);
    } else {
        dsa_fp32<<<dim3(4096), dim3(256), 0, stream>>>(q, k, v, ti, ts, out);
    }
}

// Round 6
// 142.826 us; speedup vs baseline: 1.2251x; 1.2251x over previous
//
#include <hip/hip_runtime.h>
#include <hip/hip_fp16.h>

#define NH  16
#define SQL 1024
#define SKV 4096
#define HD  128
#define TK  64

typedef _Float16 h2_t __attribute__((ext_vector_type(2)));

__device__ __forceinline__ unsigned pkh(float x, float y) {
    return (unsigned)__half_as_ushort(__float2half(x)) |
           ((unsigned)__half_as_ushort(__float2half(y)) << 16);
}

// ---- fp32 -> fp16 streaming cast, layout preserved [H][SKV][HD] ----
// blocks [0,4096): K, [4096,8192): V; 8 elems/thread
__global__ __launch_bounds__(256) void cvt_f16(
    const float* __restrict__ k, const float* __restrict__ v,
    unsigned short* __restrict__ kh, unsigned short* __restrict__ vh)
{
    int b = blockIdx.x;
    const float* src; unsigned short* dst;
    if (b < 4096) { src = k; dst = kh; }
    else          { src = v; dst = vh; b -= 4096; }
    const size_t i = (size_t)b * 256 + threadIdx.x;   // 8-elem chunk
    const float4* s4 = (const float4*)src;
    float4 a = s4[2 * i], c = s4[2 * i + 1];
    uint4 o;
    o.x = pkh(a.x, a.y);
    o.y = pkh(a.z, a.w);
    o.z = pkh(c.x, c.y);
    o.w = pkh(c.z, c.w);
    ((uint4*)dst)[i] = o;
}

// ---- combined QK->softmax->PV, fp16 gathered rows, 4 rows/instr ----
__global__ __launch_bounds__(256) void dsa_f16(
    const float* __restrict__ q, const unsigned short* __restrict__ kh,
    const unsigned short* __restrict__ vh, const int* __restrict__ tidx,
    const float* __restrict__ tsc, float* __restrict__ out)
{
    __shared__ int   idxs[4][TK];
    __shared__ float wsc[4][TK];

    const int tid  = threadIdx.x;
    const int wv   = tid >> 6;
    const int lane = tid & 63;
    const int quad = lane >> 4;    // which of 4 gathered rows this 16-lane group loads
    const int l16  = lane & 15;    // dims 8*l16 .. 8*l16+7
    const int bi   = blockIdx.x;

    // one head per XCD at a time: blocks 0..2047 -> heads 0..7 (= bi%8 = XCD)
    const int h = ((bi >> 11) << 3) | (bi & 7);
    const int s = (((bi >> 3) & 255) << 2) + wv;

    // q fragment: 8 dims of head h (fp32 load, fp16 repack for dot2)
    const float* qp = q + (size_t)(h * SQL + s) * HD + 8 * l16;
    const float4 qa = *(const float4*)qp;
    const float4 qb = *(const float4*)(qp + 4);
    h2_t q0 = {(_Float16)qa.x, (_Float16)qa.y};
    h2_t q1 = {(_Float16)qa.z, (_Float16)qa.w};
    h2_t q2 = {(_Float16)qb.x, (_Float16)qb.y};
    h2_t q3 = {(_Float16)qb.z, (_Float16)qb.w};

    idxs[wv][lane] = tidx[s * TK + lane];
    const float t_sc = tsc[s * TK + lane];

    // ---- QK^T: 4 fp16 rows per instruction (64 lanes x 16B = 4 x 256B rows)
    const unsigned short* kb = kh + (size_t)h * SKV * HD;
#pragma unroll 8
    for (int i = 0; i < TK / 4; ++i) {
        const int t   = 4 * i + quad;
        const size_t row = (size_t)idxs[wv][t];     // wave-private LDS broadcast
        uint4 kw = *(const uint4*)(kb + row * HD + 8 * l16);
        float d = 0.f;
#if __has_builtin(__builtin_amdgcn_fdot2)
        d = __builtin_amdgcn_fdot2(q0, __builtin_bit_cast(h2_t, kw.x), d, false);
        d = __builtin_amdgcn_fdot2(q1, __builtin_bit_cast(h2_t, kw.y), d, false);
        d = __builtin_amdgcn_fdot2(q2, __builtin_bit_cast(h2_t, kw.z), d, false);
        d = __builtin_amdgcn_fdot2(q3, __builtin_bit_cast(h2_t, kw.w), d, false);
#else
        {
            float2 k0 = __half22float2(__builtin_bit_cast(__half2, kw.x));
            float2 k1 = __half22float2(__builtin_bit_cast(__half2, kw.y));
            float2 k2 = __half22float2(__builtin_bit_cast(__half2, kw.z));
            float2 k3 = __half22float2(__builtin_bit_cast(__half2, kw.w));
            d  = qa.x * k0.x + qa.y * k0.y + qa.z * k1.x + qa.w * k1.y;
            d += qb.x * k2.x + qb.y * k2.y + qb.z * k3.x + qb.w * k3.y;
        }
#endif
        d += __shfl_xor(d, 8);
        d += __shfl_xor(d, 4);
        d += __shfl_xor(d, 2);
        d += __shfl_xor(d, 1);
        if (l16 == 0) wsc[wv][t] = d;               // lanes 0,16,32,48
    }

    // ---- fused softmax * topk_scores, renormalized:
    // w_t = e_t*ts_t / (sum(e*ts) + 1e-12*sum(e))
    float acc = wsc[wv][lane] * 0.08838834764831845f;   // 1/sqrt(128)
    float m = acc;
#pragma unroll
    for (int off = 32; off; off >>= 1) m = fmaxf(m, __shfl_xor(m, off));
    const float e   = __expf(acc - m);
    const float ets = e * t_sc;
    float se = e, sets = ets;
#pragma unroll
    for (int off = 32; off; off >>= 1) {
        se   += __shfl_xor(se, off);
        sets += __shfl_xor(sets, off);
    }
    wsc[wv][lane] = ets / (sets + 1e-12f * se);

    // ---- PV: 4 fp16 rows per instruction; packed v_pk_fma_f16 accumulate
    const unsigned short* vb = vh + (size_t)h * SKV * HD;
    __half2 o0 = __float2half2_rn(0.f);
    __half2 o1 = o0, o2 = o0, o3 = o0;
#pragma unroll 8
    for (int i = 0; i < TK / 4; ++i) {
        const int t    = 4 * i + quad;
        const size_t row = (size_t)idxs[wv][t];
        const __half2 w2 = __float2half2_rn(wsc[wv][t]);
        uint4 vw = *(const uint4*)(vb + row * HD + 8 * l16);
        o0 = __hfma2(w2, __builtin_bit_cast(__half2, vw.x), o0);
        o1 = __hfma2(w2, __builtin_bit_cast(__half2, vw.y), o1);
        o2 = __hfma2(w2, __builtin_bit_cast(__half2, vw.z), o2);
        o3 = __hfma2(w2, __builtin_bit_cast(__half2, vw.w), o3);
    }

    // quads hold disjoint t-subsets of the same dims -> combine in fp16 pairs
    __half2 oo[4] = {o0, o1, o2, o3};
#pragma unroll
    for (int j = 0; j < 4; ++j) {
        unsigned u = __builtin_bit_cast(unsigned, oo[j]);
        oo[j] = __hadd2(oo[j], __builtin_bit_cast(__half2, __shfl_xor(u, 16)));
        u = __builtin_bit_cast(unsigned, oo[j]);
        oo[j] = __hadd2(oo[j], __builtin_bit_cast(__half2, __shfl_xor(u, 32)));
    }

    if (quad == 0) {
        float2 f0 = __half22float2(oo[0]);
        float2 f1 = __half22float2(oo[1]);
        float2 f2 = __half22float2(oo[2]);
        float2 f3 = __half22float2(oo[3]);
        float* op = out + (size_t)(h * SQL + s) * HD + 8 * l16;
        *(float4*)op       = make_float4(f0.x, f0.y, f1.x, f1.y);
        *(float4*)(op + 4) = make_float4(f2.x, f2.y, f3.x, f3.y);
    }
}

// ---- fp32 fallback (round-1 kernel) if workspace too small ----
__global__ __launch_bounds__(256) void dsa_fp32(
    const float* __restrict__ q, const float* __restrict__ k,
    const float* __restrict__ v, const int* __restrict__ tidx,
    const float* __restrict__ tsc, float* __restrict__ out)
{
    __shared__ int   idxs[4][TK];
    __shared__ float wsc[4][TK];
    const int tid = threadIdx.x, wv = tid >> 6, lane = tid & 63;
    const int half = lane >> 5, l32 = lane & 31, bi = blockIdx.x;
    const int h = ((bi & 7) << 1) | ((bi >> 3) & 1);
    const int s = ((bi >> 4) << 2) + wv;
    const float* qp = q + (size_t)(h * SQL + s) * HD;
    const float4 qf = *(const float4*)(qp + 4 * l32);
    const float t_sc = tsc[s * TK + lane];
    idxs[wv][lane] = tidx[s * TK + lane];
    const float* kb = k + (size_t)h * SKV * HD;
#pragma unroll 4
    for (int i = 0; i < TK / 2; ++i) {
        const int t = 2 * i + half, row = idxs[wv][t];
        float4 k4 = *(const float4*)(kb + (size_t)row * HD + 4 * l32);
        float d = k4.x * qf.x + k4.y * qf.y + k4.z * qf.z + k4.w * qf.w;
        d += __shfl_xor(d, 16); d += __shfl_xor(d, 8); d += __shfl_xor(d, 4);
        d += __shfl_xor(d, 2);  d += __shfl_xor(d, 1);
        if (l32 == 0) wsc[wv][t] = d;
    }
    float acc = wsc[wv][lane] * 0.08838834764831845f;
    float m = acc;
#pragma unroll
    for (int off = 32; off; off >>= 1) m = fmaxf(m, __shfl_xor(m, off));
    const float e = __expf(acc - m), ets = e * t_sc;
    float se = e, sets = ets;
#pragma unroll
    for (int off = 32; off; off >>= 1) { se += __shfl_xor(se, off); sets += __shfl_xor(sets, off); }
    wsc[wv][lane] = ets / (sets + 1e-12f * se);
    const float* vbp = v + (size_t)h * SKV * HD;
    float4 o = make_float4(0.f, 0.f, 0.f, 0.f);
#pragma unroll 4
    for (int i = 0; i < TK / 2; ++i) {
        const int t = 2 * i + half, row = idxs[wv][t];
        const float wt = wsc[wv][t];
        float4 v4 = *(const float4*)(vbp + (size_t)row * HD + 4 * l32);
        o.x += wt * v4.x; o.y += wt * v4.y; o.z += wt * v4.z; o.w += wt * v4.w;
    }
    o.x += __shfl_xor(o.x, 32); o.y += __shfl_xor(o.y, 32);
    o.z += __shfl_xor(o.z, 32); o.w += __shfl_xor(o.w, 32);
    if (half == 0) *(float4*)(out + (size_t)(h * SQL + s) * HD + 4 * l32) = o;
}

extern "C" void kernel_launch(void* const* d_in, const int* in_sizes, int n_in,
                              void* d_out, int out_size, void* d_ws, size_t ws_size,
                              hipStream_t stream) {
    const float* q  = (const float*)d_in[0];
    const float* k  = (const float*)d_in[1];
    const float* v  = (const float*)d_in[2];
    const int*   ti = (const int*)d_in[3];
    const float* ts = (const float*)d_in[4];
    float* out = (float*)d_out;

    const size_t nkv  = (size_t)NH * SKV * HD;            // 8.4M elems each
    const size_t need = 2 * nkv * sizeof(unsigned short); // 33.6 MB
    if (ws_size >= need) {
        unsigned short* kh = (unsigned short*)d_ws;
        unsigned short* vh = kh + nkv;
        cvt_f16<<<dim3(8192), dim3(256), 0, stream>>>(k, v, kh, vh);
        dsa_f16<<<dim3(4096), dim3(256), 0, stream>>>(q, kh, vh, ti, ts, out);
    } else {
        dsa_fp32<<<dim3(4096), dim3(256), 0, stream>>>(q, k, v, ti, ts, out);
    }
}

// Round 7
// 133.585 us; speedup vs baseline: 1.3099x; 1.0692x over previous
//
#include <hip/hip_runtime.h>
#include <hip/hip_fp16.h>

#define NH  16
#define SQL 1024
#define SKV 4096
#define HD  128
#define TK  64

typedef _Float16 h2_t __attribute__((ext_vector_type(2)));

__device__ __forceinline__ unsigned pkh(float x, float y) {
    return (unsigned)__half_as_ushort(__float2half(x)) |
           ((unsigned)__half_as_ushort(__float2half(y)) << 16);
}

// ---- fp32 -> fp16 streaming cast, layout preserved [H][SKV][HD] ----
// blocks [0,4096): K, [4096,8192): V; 8 elems/thread
__global__ __launch_bounds__(256) void cvt_f16(
    const float* __restrict__ k, const float* __restrict__ v,
    unsigned short* __restrict__ kh, unsigned short* __restrict__ vh)
{
    int b = blockIdx.x;
    const float* src; unsigned short* dst;
    if (b < 4096) { src = k; dst = kh; }
    else          { src = v; dst = vh; b -= 4096; }
    const size_t i = (size_t)b * 256 + threadIdx.x;   // 8-elem chunk
    const float4* s4 = (const float4*)src;
    float4 a = s4[2 * i], c = s4[2 * i + 1];
    uint4 o;
    o.x = pkh(a.x, a.y);
    o.y = pkh(a.z, a.w);
    o.z = pkh(c.x, c.y);
    o.w = pkh(c.z, c.w);
    ((uint4*)dst)[i] = o;
}

// ---- combined QK->softmax->PV, fp16 rows, register-batched QK reduce ----
__global__ __launch_bounds__(256) void dsa_f16(
    const float* __restrict__ q, const unsigned short* __restrict__ kh,
    const unsigned short* __restrict__ vh, const int* __restrict__ tidx,
    const float* __restrict__ tsc, float* __restrict__ out)
{
    __shared__ int   idxs[4][TK];
    __shared__ float wsc[4][TK];
    __shared__ float scr[4][TK][17];   // transpose buffer; stride 17 -> <=2-way banks

    const int tid  = threadIdx.x;
    const int wv   = tid >> 6;
    const int lane = tid & 63;
    const int quad = lane >> 4;    // which of 4 gathered rows this 16-lane group loads
    const int l16  = lane & 15;    // dims 8*l16 .. 8*l16+7
    const int bi   = blockIdx.x;

    // one head per XCD at a time: blocks 0..2047 -> heads 0..7 (= bi%8 = XCD)
    const int h = ((bi >> 11) << 3) | (bi & 7);
    const int s = (((bi >> 3) & 255) << 2) + wv;

    // q fragment: 8 dims of head h (fp32 load, fp16 repack for dot2)
    const float* qp = q + (size_t)(h * SQL + s) * HD + 8 * l16;
    const float4 qa = *(const float4*)qp;
    const float4 qb = *(const float4*)(qp + 4);
    h2_t q0 = {(_Float16)qa.x, (_Float16)qa.y};
    h2_t q1 = {(_Float16)qa.z, (_Float16)qa.w};
    h2_t q2 = {(_Float16)qb.x, (_Float16)qb.y};
    h2_t q3 = {(_Float16)qb.z, (_Float16)qb.w};

    idxs[wv][lane] = tidx[s * TK + lane];
    const float t_sc = tsc[s * TK + lane];

    // ---- QK^T: 4 fp16 rows/instr; NO cross-lane ops in the loop.
    // 16 independent load->dot2 chains; partials parked in registers.
    const unsigned short* kb = kh + (size_t)h * SKV * HD;
    float part[16];
#pragma unroll
    for (int i = 0; i < 16; ++i) {
        const int t   = 4 * i + quad;
        const size_t row = (size_t)idxs[wv][t];
        uint4 kw = *(const uint4*)(kb + row * HD + 8 * l16);
        float d = 0.f;
#if __has_builtin(__builtin_amdgcn_fdot2)
        d = __builtin_amdgcn_fdot2(q0, __builtin_bit_cast(h2_t, kw.x), d, false);
        d = __builtin_amdgcn_fdot2(q1, __builtin_bit_cast(h2_t, kw.y), d, false);
        d = __builtin_amdgcn_fdot2(q2, __builtin_bit_cast(h2_t, kw.z), d, false);
        d = __builtin_amdgcn_fdot2(q3, __builtin_bit_cast(h2_t, kw.w), d, false);
#else
        {
            float2 k0 = __half22float2(__builtin_bit_cast(__half2, kw.x));
            float2 k1 = __half22float2(__builtin_bit_cast(__half2, kw.y));
            float2 k2 = __half22float2(__builtin_bit_cast(__half2, kw.z));
            float2 k3 = __half22float2(__builtin_bit_cast(__half2, kw.w));
            d  = qa.x * k0.x + qa.y * k0.y + qa.z * k1.x + qa.w * k1.y;
            d += qb.x * k2.x + qb.y * k2.y + qb.z * k3.x + qb.w * k3.y;
        }
#endif
        part[i] = d;
    }

    // one LDS transpose (wave-private rows -> no barrier): lane j ends up
    // owning score for t=j, exactly the softmax layout.
#pragma unroll
    for (int i = 0; i < 16; ++i) scr[wv][4 * i + quad][l16] = part[i];
    float acc = 0.f;
#pragma unroll
    for (int m = 0; m < 16; ++m) acc += scr[wv][lane][m];
    acc *= 0.08838834764831845f;                        // 1/sqrt(128)

    // ---- fused softmax * topk_scores, renormalized:
    // w_t = e_t*ts_t / (sum(e*ts) + 1e-12*sum(e))
    float m = acc;
#pragma unroll
    for (int off = 32; off; off >>= 1) m = fmaxf(m, __shfl_xor(m, off));
    const float e   = __expf(acc - m);
    const float ets = e * t_sc;
    float se = e, sets = ets;
#pragma unroll
    for (int off = 32; off; off >>= 1) {
        se   += __shfl_xor(se, off);
        sets += __shfl_xor(sets, off);
    }
    wsc[wv][lane] = ets / (sets + 1e-12f * se);

    // ---- PV: 4 fp16 rows per instruction; packed v_pk_fma_f16 accumulate
    const unsigned short* vb = vh + (size_t)h * SKV * HD;
    __half2 o0 = __float2half2_rn(0.f);
    __half2 o1 = o0, o2 = o0, o3 = o0;
#pragma unroll 8
    for (int i = 0; i < TK / 4; ++i) {
        const int t    = 4 * i + quad;
        const size_t row = (size_t)idxs[wv][t];
        const __half2 w2 = __float2half2_rn(wsc[wv][t]);
        uint4 vw = *(const uint4*)(vb + row * HD + 8 * l16);
        o0 = __hfma2(w2, __builtin_bit_cast(__half2, vw.x), o0);
        o1 = __hfma2(w2, __builtin_bit_cast(__half2, vw.y), o1);
        o2 = __hfma2(w2, __builtin_bit_cast(__half2, vw.z), o2);
        o3 = __hfma2(w2, __builtin_bit_cast(__half2, vw.w), o3);
    }

    // quads hold disjoint t-subsets of the same dims -> combine in fp16 pairs
    __half2 oo[4] = {o0, o1, o2, o3};
#pragma unroll
    for (int j = 0; j < 4; ++j) {
        unsigned u = __builtin_bit_cast(unsigned, oo[j]);
        oo[j] = __hadd2(oo[j], __builtin_bit_cast(__half2, __shfl_xor(u, 16)));
        u = __builtin_bit_cast(unsigned, oo[j]);
        oo[j] = __hadd2(oo[j], __builtin_bit_cast(__half2, __shfl_xor(u, 32)));
    }

    if (quad == 0) {
        float2 f0 = __half22float2(oo[0]);
        float2 f1 = __half22float2(oo[1]);
        float2 f2 = __half22float2(oo[2]);
        float2 f3 = __half22float2(oo[3]);
        float* op = out + (size_t)(h * SQL + s) * HD + 8 * l16;
        *(float4*)op       = make_float4(f0.x, f0.y, f1.x, f1.y);
        *(float4*)(op + 4) = make_float4(f2.x, f2.y, f3.x, f3.y);
    }
}

// ---- fp32 fallback (round-1 kernel) if workspace too small ----
__global__ __launch_bounds__(256) void dsa_fp32(
    const float* __restrict__ q, const float* __restrict__ k,
    const float* __restrict__ v, const int* __restrict__ tidx,
    const float* __restrict__ tsc, float* __restrict__ out)
{
    __shared__ int   idxs[4][TK];
    __shared__ float wsc[4][TK];
    const int tid = threadIdx.x, wv = tid >> 6, lane = tid & 63;
    const int half = lane >> 5, l32 = lane & 31, bi = blockIdx.x;
    const int h = ((bi & 7) << 1) | ((bi >> 3) & 1);
    const int s = ((bi >> 4) << 2) + wv;
    const float* qp = q + (size_t)(h * SQL + s) * HD;
    const float4 qf = *(const float4*)(qp + 4 * l32);
    const float t_sc = tsc[s * TK + lane];
    idxs[wv][lane] = tidx[s * TK + lane];
    const float* kb = k + (size_t)h * SKV * HD;
#pragma unroll 4
    for (int i = 0; i < TK / 2; ++i) {
        const int t = 2 * i + half, row = idxs[wv][t];
        float4 k4 = *(const float4*)(kb + (size_t)row * HD + 4 * l32);
        float d = k4.x * qf.x + k4.y * qf.y + k4.z * qf.z + k4.w * qf.w;
        d += __shfl_xor(d, 16); d += __shfl_xor(d, 8); d += __shfl_xor(d, 4);
        d += __shfl_xor(d, 2);  d += __shfl_xor(d, 1);
        if (l32 == 0) wsc[wv][t] = d;
    }
    float acc = wsc[wv][lane] * 0.08838834764831845f;
    float m = acc;
#pragma unroll
    for (int off = 32; off; off >>= 1) m = fmaxf(m, __shfl_xor(m, off));
    const float e = __expf(acc - m), ets = e * t_sc;
    float se = e, sets = ets;
#pragma unroll
    for (int off = 32; off; off >>= 1) { se += __shfl_xor(se, off); sets += __shfl_xor(sets, off); }
    wsc[wv][lane] = ets / (sets + 1e-12f * se);
    const float* vbp = v + (size_t)h * SKV * HD;
    float4 o = make_float4(0.f, 0.f, 0.f, 0.f);
#pragma unroll 4
    for (int i = 0; i < TK / 2; ++i) {
        const int t = 2 * i + half, row = idxs[wv][t];
        const float wt = wsc[wv][t];
        float4 v4 = *(const float4*)(vbp + (size_t)row * HD + 4 * l32);
        o.x += wt * v4.x; o.y += wt * v4.y; o.z += wt * v4.z; o.w += wt * v4.w;
    }
    o.x += __shfl_xor(o.x, 32); o.y += __shfl_xor(o.y, 32);
    o.z += __shfl_xor(o.z, 32); o.w += __shfl_xor(o.w, 32);
    if (half == 0) *(float4*)(out + (size_t)(h * SQL + s) * HD + 4 * l32) = o;
}

extern "C" void kernel_launch(void* const* d_in, const int* in_sizes, int n_in,
                              void* d_out, int out_size, void* d_ws, size_t ws_size,
                              hipStream_t stream) {
    const float* q  = (const float*)d_in[0];
    const float* k  = (const float*)d_in[1];
    const float* v  = (const float*)d_in[2];
    const int*   ti = (const int*)d_in[3];
    const float* ts = (const float*)d_in[4];
    float* out = (float*)d_out;

    const size_t nkv  = (size_t)NH * SKV * HD;            // 8.4M elems each
    const size_t need = 2 * nkv * sizeof(unsigned short); // 33.6 MB
    if (ws_size >= need) {
        unsigned short* kh = (unsigned short*)d_ws;
        unsigned short* vh = kh + nkv;
        cvt_f16<<<dim3(8192), dim3(256), 0, stream>>>(k, v, kh, vh);
        dsa_f16<<<dim3(4096), dim3(256), 0, stream>>>(q, kh, vh, ti, ts, out);
    } else {
        dsa_fp32<<<dim3(4096), dim3(256), 0, stream>>>(q, k, v, ti, ts, out);
    }
}

// Round 8
// 133.214 us; speedup vs baseline: 1.3135x; 1.0028x over previous
//
#include <hip/hip_runtime.h>
#include <hip/hip_fp16.h>

#define NH  16
#define SQL 1024
#define SKV 4096
#define HD  128
#define TK  64

typedef _Float16 h2_t __attribute__((ext_vector_type(2)));

__device__ __forceinline__ unsigned pkh(float x, float y) {
    return (unsigned)__half_as_ushort(__float2half(x)) |
           ((unsigned)__half_as_ushort(__float2half(y)) << 16);
}

// ---- fp32 -> fp16 streaming cast, layout preserved [H][SKV][HD] ----
// blocks [0,4096): K, [4096,8192): V; 8 elems/thread
__global__ __launch_bounds__(256) void cvt_f16(
    const float* __restrict__ k, const float* __restrict__ v,
    unsigned short* __restrict__ kh, unsigned short* __restrict__ vh)
{
    int b = blockIdx.x;
    const float* src; unsigned short* dst;
    if (b < 4096) { src = k; dst = kh; }
    else          { src = v; dst = vh; b -= 4096; }
    const size_t i = (size_t)b * 256 + threadIdx.x;   // 8-elem chunk
    const float4* s4 = (const float4*)src;
    float4 a = s4[2 * i], c = s4[2 * i + 1];
    uint4 o;
    o.x = pkh(a.x, a.y);
    o.y = pkh(a.z, a.w);
    o.z = pkh(c.x, c.y);
    o.w = pkh(c.z, c.w);
    ((uint4*)dst)[i] = o;
}

// ---- combined QK->softmax->PV; V gathers issued early and kept in
// registers so their latency overlaps transpose+softmax (single fused
// memory phase per wave) ----
__global__ __launch_bounds__(256) void dsa_f16(
    const float* __restrict__ q, const unsigned short* __restrict__ kh,
    const unsigned short* __restrict__ vh, const int* __restrict__ tidx,
    const float* __restrict__ tsc, float* __restrict__ out)
{
    __shared__ float scr[4][TK][17];   // transpose buffer; wave-private rows

    const int tid  = threadIdx.x;
    const int wv   = tid >> 6;
    const int lane = tid & 63;
    const int quad = lane >> 4;    // which of 4 gathered rows this 16-lane group loads
    const int l16  = lane & 15;    // dims 8*l16 .. 8*l16+7
    const int bi   = blockIdx.x;

    // one head per XCD at a time: blocks 0..2047 -> heads 0..7 (= bi%8 = XCD)
    const int h = ((bi >> 11) << 3) | (bi & 7);
    const int s = (((bi >> 3) & 255) << 2) + wv;

    // q fragment: 8 dims of head h (fp32 load, fp16 repack for dot2)
    const float* qp = q + (size_t)(h * SQL + s) * HD + 8 * l16;
    const float4 qa = *(const float4*)qp;
    const float4 qb = *(const float4*)(qp + 4);
    h2_t q0 = {(_Float16)qa.x, (_Float16)qa.y};
    h2_t q1 = {(_Float16)qa.z, (_Float16)qa.w};
    h2_t q2 = {(_Float16)qb.x, (_Float16)qb.y};
    h2_t q3 = {(_Float16)qb.z, (_Float16)qb.w};

    // lane t owns topk entry t; broadcasts via __shfl (no LDS round-trip)
    const int   t_idx = tidx[s * TK + lane];
    const float t_sc  = tsc[s * TK + lane];

    // ---- QK^T: 16 independent gathered-row loads, partials in registers
    const unsigned short* kb = kh + (size_t)h * SKV * HD;
    float part[16];
#pragma unroll
    for (int i = 0; i < 16; ++i) {
        const size_t row = (size_t)__shfl(t_idx, 4 * i + quad);
        uint4 kw = *(const uint4*)(kb + row * HD + 8 * l16);
        float d = 0.f;
#if __has_builtin(__builtin_amdgcn_fdot2)
        d = __builtin_amdgcn_fdot2(q0, __builtin_bit_cast(h2_t, kw.x), d, false);
        d = __builtin_amdgcn_fdot2(q1, __builtin_bit_cast(h2_t, kw.y), d, false);
        d = __builtin_amdgcn_fdot2(q2, __builtin_bit_cast(h2_t, kw.z), d, false);
        d = __builtin_amdgcn_fdot2(q3, __builtin_bit_cast(h2_t, kw.w), d, false);
#else
        {
            float2 k0 = __half22float2(__builtin_bit_cast(__half2, kw.x));
            float2 k1 = __half22float2(__builtin_bit_cast(__half2, kw.y));
            float2 k2 = __half22float2(__builtin_bit_cast(__half2, kw.z));
            float2 k3 = __half22float2(__builtin_bit_cast(__half2, kw.w));
            d  = qa.x * k0.x + qa.y * k0.y + qa.z * k1.x + qa.w * k1.y;
            d += qb.x * k2.x + qb.y * k2.y + qb.z * k3.x + qb.w * k3.y;
        }
#endif
        part[i] = d;
    }

    // ---- issue ALL V gathers now; latency hides behind transpose+softmax
    const unsigned short* vb = vh + (size_t)h * SKV * HD;
    uint4 vw[16];
#pragma unroll
    for (int i = 0; i < 16; ++i) {
        const size_t row = (size_t)__shfl(t_idx, 4 * i + quad);
        vw[i] = *(const uint4*)(vb + row * HD + 8 * l16);
    }

    // one LDS transpose (wave-private rows -> no barrier): lane j ends up
    // owning score for t=j, exactly the softmax layout.
#pragma unroll
    for (int i = 0; i < 16; ++i) scr[wv][4 * i + quad][l16] = part[i];
    float acc = 0.f;
#pragma unroll
    for (int m = 0; m < 16; ++m) acc += scr[wv][lane][m];
    acc *= 0.08838834764831845f;                        // 1/sqrt(128)

    // ---- fused softmax * topk_scores, renormalized:
    // w_t = e_t*ts_t / (sum(e*ts) + 1e-12*sum(e))
    float m = acc;
#pragma unroll
    for (int off = 32; off; off >>= 1) m = fmaxf(m, __shfl_xor(m, off));
    const float e   = __expf(acc - m);
    const float ets = e * t_sc;
    float se = e, sets = ets;
#pragma unroll
    for (int off = 32; off; off >>= 1) {
        se   += __shfl_xor(se, off);
        sets += __shfl_xor(sets, off);
    }
    const float w = ets / (sets + 1e-12f * se);
    const unsigned wpk = __builtin_bit_cast(unsigned, __float2half2_rn(w));

    // ---- PV consume from registers; weight broadcast via __shfl
    __half2 o0 = __float2half2_rn(0.f);
    __half2 o1 = o0, o2 = o0, o3 = o0;
#pragma unroll
    for (int i = 0; i < 16; ++i) {
        const __half2 w2 = __builtin_bit_cast(__half2, __shfl(wpk, 4 * i + quad));
        o0 = __hfma2(w2, __builtin_bit_cast(__half2, vw[i].x), o0);
        o1 = __hfma2(w2, __builtin_bit_cast(__half2, vw[i].y), o1);
        o2 = __hfma2(w2, __builtin_bit_cast(__half2, vw[i].z), o2);
        o3 = __hfma2(w2, __builtin_bit_cast(__half2, vw[i].w), o3);
    }

    // quads hold disjoint t-subsets of the same dims -> combine in fp16 pairs
    __half2 oo[4] = {o0, o1, o2, o3};
#pragma unroll
    for (int j = 0; j < 4; ++j) {
        unsigned u = __builtin_bit_cast(unsigned, oo[j]);
        oo[j] = __hadd2(oo[j], __builtin_bit_cast(__half2, __shfl_xor(u, 16)));
        u = __builtin_bit_cast(unsigned, oo[j]);
        oo[j] = __hadd2(oo[j], __builtin_bit_cast(__half2, __shfl_xor(u, 32)));
    }

    if (quad == 0) {
        float2 f0 = __half22float2(oo[0]);
        float2 f1 = __half22float2(oo[1]);
        float2 f2 = __half22float2(oo[2]);
        float2 f3 = __half22float2(oo[3]);
        float* op = out + (size_t)(h * SQL + s) * HD + 8 * l16;
        *(float4*)op       = make_float4(f0.x, f0.y, f1.x, f1.y);
        *(float4*)(op + 4) = make_float4(f2.x, f2.y, f3.x, f3.y);
    }
}

// ---- fp32 fallback (round-1 kernel) if workspace too small ----
__global__ __launch_bounds__(256) void dsa_fp32(
    const float* __restrict__ q, const float* __restrict__ k,
    const float* __restrict__ v, const int* __restrict__ tidx,
    const float* __restrict__ tsc, float* __restrict__ out)
{
    __shared__ int   idxs[4][TK];
    __shared__ float wsc[4][TK];
    const int tid = threadIdx.x, wv = tid >> 6, lane = tid & 63;
    const int half = lane >> 5, l32 = lane & 31, bi = blockIdx.x;
    const int h = ((bi & 7) << 1) | ((bi >> 3) & 1);
    const int s = ((bi >> 4) << 2) + wv;
    const float* qp = q + (size_t)(h * SQL + s) * HD;
    const float4 qf = *(const float4*)(qp + 4 * l32);
    const float t_sc = tsc[s * TK + lane];
    idxs[wv][lane] = tidx[s * TK + lane];
    const float* kb = k + (size_t)h * SKV * HD;
#pragma unroll 4
    for (int i = 0; i < TK / 2; ++i) {
        const int t = 2 * i + half, row = idxs[wv][t];
        float4 k4 = *(const float4*)(kb + (size_t)row * HD + 4 * l32);
        float d = k4.x * qf.x + k4.y * qf.y + k4.z * qf.z + k4.w * qf.w;
        d += __shfl_xor(d, 16); d += __shfl_xor(d, 8); d += __shfl_xor(d, 4);
        d += __shfl_xor(d, 2);  d += __shfl_xor(d, 1);
        if (l32 == 0) wsc[wv][t] = d;
    }
    float acc = wsc[wv][lane] * 0.08838834764831845f;
    float m = acc;
#pragma unroll
    for (int off = 32; off; off >>= 1) m = fmaxf(m, __shfl_xor(m, off));
    const float e = __expf(acc - m), ets = e * t_sc;
    float se = e, sets = ets;
#pragma unroll
    for (int off = 32; off; off >>= 1) { se += __shfl_xor(se, off); sets += __shfl_xor(sets, off); }
    wsc[wv][lane] = ets / (sets + 1e-12f * se);
    const float* vbp = v + (size_t)h * SKV * HD;
    float4 o = make_float4(0.f, 0.f, 0.f, 0.f);
#pragma unroll 4
    for (int i = 0; i < TK / 2; ++i) {
        const int t = 2 * i + half, row = idxs[wv][t];
        const float wt = wsc[wv][t];
        float4 v4 = *(const float4*)(vbp + (size_t)row * HD + 4 * l32);
        o.x += wt * v4.x; o.y += wt * v4.y; o.z += wt * v4.z; o.w += wt * v4.w;
    }
    o.x += __shfl_xor(o.x, 32); o.y += __shfl_xor(o.y, 32);
    o.z += __shfl_xor(o.z, 32); o.w += __shfl_xor(o.w, 32);
    if (half == 0) *(float4*)(out + (size_t)(h * SQL + s) * HD + 4 * l32) = o;
}

extern "C" void kernel_launch(void* const* d_in, const int* in_sizes, int n_in,
                              void* d_out, int out_size, void* d_ws, size_t ws_size,
                              hipStream_t stream) {
    const float* q  = (const float*)d_in[0];
    const float* k  = (const float*)d_in[1];
    const float* v  = (const float*)d_in[2];
    const int*   ti = (const int*)d_in[3];
    const float* ts = (const float*)d_in[4];
    float* out = (float*)d_out;

    const size_t nkv  = (size_t)NH * SKV * HD;            // 8.4M elems each
    const size_t need = 2 * nkv * sizeof(unsigned short); // 33.6 MB
    if (ws_size >= need) {
        unsigned short* kh = (unsigned short*)d_ws;
        unsigned short* vh = kh + nkv;
        cvt_f16<<<dim3(8192), dim3(256), 0, stream>>>(k, v, kh, vh);
        dsa_f16<<<dim3(4096), dim3(256), 0, stream>>>(q, kh, vh, ti, ts, out);
    } else {
        dsa_fp32<<<dim3(4096), dim3(256), 0, stream>>>(q, k, v, ti, ts, out);
    }
}